// Round 3
// baseline (279.512 us; speedup 1.0000x reference)
//
#include <hip/hip_runtime.h>

#define NLVL  9
#define NPTS  262144
#define NBUCK 4096   // 16 x 16 x 16 Morton buckets

// ---- ws layout (bytes) ----
// [0      , 16384 )  hist   (4096 u32)
// [16384  , 32768 )  offs   (4096 u32)
// [32768  , 32768+1M)  bucket id per point (262144 u32)
// [32768+1M, 32768+2M) perm  (262144 u32)
#define WS_HIST(ws)   ((unsigned*)(ws))
#define WS_OFFS(ws)   ((unsigned*)((char*)(ws) + 16384))
#define WS_BUCKET(ws) ((unsigned*)((char*)(ws) + 32768))
#define WS_PERM(ws)   ((unsigned*)((char*)(ws) + 32768 + (NPTS * 4)))

__device__ __forceinline__ unsigned part3_4(unsigned v) {
    // spread 4 bits to every 3rd position (bits 0,3,6,9)
    v &= 0xFu;
    v = (v | (v << 4)) & 0x0C3u;
    v = (v | (v << 2)) & 0x249u;
    return v;
}

__device__ __forceinline__ unsigned bucket_of(float px, float py, float pz) {
    int bx = (int)((px + 1.0f) * 8.0f);  // 16 buckets over [-1,1]
    int by = (int)((py + 1.0f) * 8.0f);
    int bz = (int)((pz + 1.0f) * 8.0f);
    bx = min(max(bx, 0), 15); by = min(max(by, 0), 15); bz = min(max(bz, 0), 15);
    return part3_4((unsigned)bx) | (part3_4((unsigned)by) << 1) | (part3_4((unsigned)bz) << 2);
}

__global__ __launch_bounds__(256) void hist_kernel(
    const float* __restrict__ x, unsigned* __restrict__ hist, unsigned* __restrict__ bucket)
{
    const int p = blockIdx.x * blockDim.x + threadIdx.x;
    if (p >= NPTS) return;
    const unsigned b = bucket_of(x[p * 3 + 0], x[p * 3 + 1], x[p * 3 + 2]);
    bucket[p] = b;
    atomicAdd(&hist[b], 1u);
}

__global__ __launch_bounds__(256) void scan_kernel(
    const unsigned* __restrict__ hist, unsigned* __restrict__ offs)
{
    // 256 threads, 16 buckets each: sequential + Hillis-Steele block scan
    __shared__ unsigned sums[256];
    const int t = threadIdx.x;
    unsigned local[16];
    unsigned s = 0;
    #pragma unroll
    for (int i = 0; i < 16; ++i) { local[i] = hist[t * 16 + i]; s += local[i]; }
    sums[t] = s;
    __syncthreads();
    for (int d = 1; d < 256; d <<= 1) {
        unsigned add = (t >= d) ? sums[t - d] : 0u;
        __syncthreads();
        sums[t] += add;
        __syncthreads();
    }
    unsigned excl = (t == 0) ? 0u : sums[t - 1];
    #pragma unroll
    for (int i = 0; i < 16; ++i) { offs[t * 16 + i] = excl; excl += local[i]; }
}

__global__ __launch_bounds__(256) void scatter_kernel(
    const unsigned* __restrict__ bucket, unsigned* __restrict__ offs, unsigned* __restrict__ perm)
{
    const int p = blockIdx.x * blockDim.x + threadIdx.x;
    if (p >= NPTS) return;
    const unsigned b = bucket[p];
    const unsigned pos = atomicAdd(&offs[b], 1u);
    perm[pos] = (unsigned)p;
}

__global__ __launch_bounds__(256) void hashgrid_enc_kernel(
    const float* __restrict__ x,
    const float* __restrict__ table,
    const unsigned* __restrict__ perm,
    float* __restrict__ out)
{
    const int tid = blockIdx.x * blockDim.x + threadIdx.x;
    if (tid >= NPTS * NLVL) return;
    const int sp = tid / NLVL;          // sorted position
    const int l  = tid - sp * NLVL;     // level
    const int p  = (int)perm[sp];       // original point index (9 lanes share)

    const float px = x[p * 3 + 0];
    const float py = x[p * 3 + 1];
    const float pz = x[p * 3 + 2];

    const int   s  = 1 << l;
    const float vs = (float)s;

    const float gx = (px + 1.0f) * 0.5f * vs;
    const float gy = (py + 1.0f) * 0.5f * vs;
    const float gz = (pz + 1.0f) * 0.5f * vs;

    const float bxf = floorf(gx);
    const float byf = floorf(gy);
    const float bzf = floorf(gz);

    const int ix = (int)bxf;
    const int iy = (int)byf;
    const int iz = (int)bzf;

    // (px - x1)/(x2 - x1) == frac(g) exactly (algebraic identity)
    const float tx = gx - bxf;
    const float ty = gy - byf;
    const float tz = gz - bzf;
    const float ux = 1.0f - tx;
    const float uy = 1.0f - ty;
    const float uz = 1.0f - tz;

    const int s2   = s * s;
    const int f000 = ix + iy * s + iz * s2;

    const float2* __restrict__ tb = (const float2*)table;

    const float2 q0 = tb[f000];
    const float2 q1 = tb[f000 + 1];
    const float2 q2 = tb[f000 + s];
    const float2 q3 = tb[f000 + s + 1];
    const float2 q4 = tb[f000 + s2];
    const float2 q5 = tb[f000 + s2 + 1];
    const float2 q6 = tb[f000 + s2 + s];
    const float2 q7 = tb[f000 + s2 + s + 1];

    const float fx0a = ux * q0.x + tx * q1.x;
    const float fx0b = ux * q0.y + tx * q1.y;
    const float fx1a = ux * q2.x + tx * q3.x;
    const float fx1b = ux * q2.y + tx * q3.y;
    const float fx2a = ux * q4.x + tx * q5.x;
    const float fx2b = ux * q4.y + tx * q5.y;
    const float fx3a = ux * q6.x + tx * q7.x;
    const float fx3b = ux * q6.y + tx * q7.y;

    const float fy0a = uy * fx0a + ty * fx1a;
    const float fy0b = uy * fx0b + ty * fx1b;
    const float fy1a = uy * fx2a + ty * fx3a;
    const float fy1b = uy * fx2b + ty * fx3b;

    float2 r;
    r.x = uz * fy0a + tz * fy1a;
    r.y = uz * fy0b + tz * fy1b;

    // scattered per-point store: out[(p*9 + l)] as float2 (72B contiguous per point)
    ((float2*)out)[p * NLVL + l] = r;
}

extern "C" void kernel_launch(void* const* d_in, const int* in_sizes, int n_in,
                              void* d_out, int out_size, void* d_ws, size_t ws_size,
                              hipStream_t stream) {
    const float* x     = (const float*)d_in[0];
    const float* table = (const float*)d_in[1];
    float* out = (float*)d_out;

    unsigned* hist   = WS_HIST(d_ws);
    unsigned* offs   = WS_OFFS(d_ws);
    unsigned* bucket = WS_BUCKET(d_ws);
    unsigned* perm   = WS_PERM(d_ws);

    hipMemsetAsync(hist, 0, NBUCK * sizeof(unsigned), stream);

    const int pb = 256;
    hist_kernel<<<(NPTS + pb - 1) / pb, pb, 0, stream>>>(x, hist, bucket);
    scan_kernel<<<1, 256, 0, stream>>>(hist, offs);
    scatter_kernel<<<(NPTS + pb - 1) / pb, pb, 0, stream>>>(bucket, offs, perm);

    const int total = NPTS * NLVL;
    hashgrid_enc_kernel<<<(total + pb - 1) / pb, pb, 0, stream>>>(x, table, perm, out);
}

// Round 4
// 275.625 us; speedup vs baseline: 1.0141x; 1.0141x over previous
//
#include <hip/hip_runtime.h>

#define NLVL  9
#define NPTS  262144
#define NBUCK 32768   // 32 x 32 x 32 Morton buckets

// ---- ws layout (bytes) ----
#define WS_HIST(ws)   ((unsigned*)(ws))                                   // 128 KB
#define WS_OFFS(ws)   ((unsigned*)((char*)(ws) + 131072))                 // 128 KB
#define WS_BUCKET(ws) ((unsigned*)((char*)(ws) + 262144))                 // 1 MB
#define WS_PERM(ws)   ((unsigned*)((char*)(ws) + 262144 + 1048576))       // 1 MB
#define WS_XS(ws)     ((float4*)  ((char*)(ws) + 262144 + 2097152))       // 4 MB

__device__ __forceinline__ unsigned part3(unsigned v) {
    // spread low 10 bits to every 3rd bit
    v &= 0x3FFu;
    v = (v | (v << 16)) & 0x30000FFu;
    v = (v | (v << 8))  & 0x300F00Fu;
    v = (v | (v << 4))  & 0x30C30C3u;
    v = (v | (v << 2))  & 0x9249249u;
    return v;
}

__device__ __forceinline__ unsigned bucket_of(float px, float py, float pz) {
    int bx = (int)((px + 1.0f) * 16.0f);  // 32 buckets per axis over [-1,1]
    int by = (int)((py + 1.0f) * 16.0f);
    int bz = (int)((pz + 1.0f) * 16.0f);
    bx = min(max(bx, 0), 31); by = min(max(by, 0), 31); bz = min(max(bz, 0), 31);
    return part3((unsigned)bx) | (part3((unsigned)by) << 1) | (part3((unsigned)bz) << 2);
}

__global__ __launch_bounds__(256) void hist_kernel(
    const float* __restrict__ x, unsigned* __restrict__ hist, unsigned* __restrict__ bucket)
{
    const int p = blockIdx.x * blockDim.x + threadIdx.x;
    if (p >= NPTS) return;
    const unsigned b = bucket_of(x[p * 3 + 0], x[p * 3 + 1], x[p * 3 + 2]);
    bucket[p] = b;
    atomicAdd(&hist[b], 1u);
}

__global__ __launch_bounds__(256) void scan_kernel(
    const unsigned* __restrict__ hist, unsigned* __restrict__ offs)
{
    // 256 threads x 128 buckets each: streaming sum + Hillis-Steele block scan + re-read
    __shared__ unsigned sums[256];
    const int t = threadIdx.x;
    unsigned s = 0;
    for (int i = 0; i < NBUCK / 256; ++i) s += hist[t * (NBUCK / 256) + i];
    sums[t] = s;
    __syncthreads();
    for (int d = 1; d < 256; d <<= 1) {
        unsigned add = (t >= d) ? sums[t - d] : 0u;
        __syncthreads();
        sums[t] += add;
        __syncthreads();
    }
    unsigned excl = (t == 0) ? 0u : sums[t - 1];
    for (int i = 0; i < NBUCK / 256; ++i) {
        offs[t * (NBUCK / 256) + i] = excl;
        excl += hist[t * (NBUCK / 256) + i];
    }
}

__global__ __launch_bounds__(256) void scatter_kernel(
    const float* __restrict__ x,
    const unsigned* __restrict__ bucket, unsigned* __restrict__ offs,
    unsigned* __restrict__ perm, float4* __restrict__ xs)
{
    const int p = blockIdx.x * blockDim.x + threadIdx.x;
    if (p >= NPTS) return;
    const unsigned b = bucket[p];
    const unsigned pos = atomicAdd(&offs[b], 1u);
    perm[pos] = (unsigned)p;
    float4 v;
    v.x = x[p * 3 + 0];
    v.y = x[p * 3 + 1];
    v.z = x[p * 3 + 2];
    v.w = 0.0f;
    xs[pos] = v;
}

__global__ __launch_bounds__(256) void enc_kernel(
    const float4* __restrict__ xs,
    const unsigned* __restrict__ perm,
    const float* __restrict__ table,
    float* __restrict__ out)
{
    const int sp = blockIdx.x * blockDim.x + threadIdx.x;
    if (sp >= NPTS) return;

    const float4 P = xs[sp];               // coalesced
    const int    p = (int)perm[sp];        // coalesced

    // norm in [0,1)
    const float nx = (P.x + 1.0f) * 0.5f;
    const float ny = (P.y + 1.0f) * 0.5f;
    const float nz = (P.z + 1.0f) * 0.5f;

    const float2* __restrict__ tb = (const float2*)table;

    float2 res[NLVL];

    #pragma unroll
    for (int l = 0; l < NLVL; ++l) {
        const int   s  = 1 << l;
        const float vs = (float)s;

        const float gx = nx * vs;
        const float gy = ny * vs;
        const float gz = nz * vs;

        const float bxf = floorf(gx);
        const float byf = floorf(gy);
        const float bzf = floorf(gz);

        const int ix = (int)bxf;
        const int iy = (int)byf;
        const int iz = (int)bzf;

        // (px - x1)/(x2 - x1) == frac(g) exactly
        const float tx = gx - bxf;
        const float ty = gy - byf;
        const float tz = gz - bzf;
        const float ux = 1.0f - tx;
        const float uy = 1.0f - ty;
        const float uz = 1.0f - tz;

        const int s2   = s * s;
        const int f000 = ix + iy * s + iz * s2;

        const float2 q0 = tb[f000];
        const float2 q1 = tb[f000 + 1];
        const float2 q2 = tb[f000 + s];
        const float2 q3 = tb[f000 + s + 1];
        const float2 q4 = tb[f000 + s2];
        const float2 q5 = tb[f000 + s2 + 1];
        const float2 q6 = tb[f000 + s2 + s];
        const float2 q7 = tb[f000 + s2 + s + 1];

        const float fx0a = ux * q0.x + tx * q1.x;
        const float fx0b = ux * q0.y + tx * q1.y;
        const float fx1a = ux * q2.x + tx * q3.x;
        const float fx1b = ux * q2.y + tx * q3.y;
        const float fx2a = ux * q4.x + tx * q5.x;
        const float fx2b = ux * q4.y + tx * q5.y;
        const float fx3a = ux * q6.x + tx * q7.x;
        const float fx3b = ux * q6.y + tx * q7.y;

        const float fy0a = uy * fx0a + ty * fx1a;
        const float fy0b = uy * fx0b + ty * fx1b;
        const float fy1a = uy * fx2a + ty * fx3a;
        const float fy1b = uy * fx2b + ty * fx3b;

        res[l].x = uz * fy0a + tz * fy1a;
        res[l].y = uz * fy0b + tz * fy1b;
    }

    float2* o = (float2*)out + (size_t)p * NLVL;   // 72 B contiguous per point
    #pragma unroll
    for (int l = 0; l < NLVL; ++l) o[l] = res[l];
}

extern "C" void kernel_launch(void* const* d_in, const int* in_sizes, int n_in,
                              void* d_out, int out_size, void* d_ws, size_t ws_size,
                              hipStream_t stream) {
    const float* x     = (const float*)d_in[0];
    const float* table = (const float*)d_in[1];
    float* out = (float*)d_out;

    unsigned* hist   = WS_HIST(d_ws);
    unsigned* offs   = WS_OFFS(d_ws);
    unsigned* bucket = WS_BUCKET(d_ws);
    unsigned* perm   = WS_PERM(d_ws);
    float4*   xs     = WS_XS(d_ws);

    hipMemsetAsync(hist, 0, NBUCK * sizeof(unsigned), stream);

    const int pb = 256;
    hist_kernel<<<(NPTS + pb - 1) / pb, pb, 0, stream>>>(x, hist, bucket);
    scan_kernel<<<1, 256, 0, stream>>>(hist, offs);
    scatter_kernel<<<(NPTS + pb - 1) / pb, pb, 0, stream>>>(x, bucket, offs, perm, xs);
    enc_kernel<<<(NPTS + pb - 1) / pb, pb, 0, stream>>>(xs, perm, table, out);
}

// Round 5
// 243.940 us; speedup vs baseline: 1.1458x; 1.1299x over previous
//
#include <hip/hip_runtime.h>

#define NLVL 9
#define NPTS 262144

__global__ __launch_bounds__(256) void enc_kernel(
    const float* __restrict__ x,
    const float* __restrict__ table,
    float* __restrict__ out)
{
    const int p = blockIdx.x * blockDim.x + threadIdx.x;
    if (p >= NPTS) return;

    // coalesced-ish 12 B/thread point load
    const float px = x[p * 3 + 0];
    const float py = x[p * 3 + 1];
    const float pz = x[p * 3 + 2];

    // norm in [0,1)
    const float nx = (px + 1.0f) * 0.5f;
    const float ny = (py + 1.0f) * 0.5f;
    const float nz = (pz + 1.0f) * 0.5f;

    const float2* __restrict__ tb = (const float2*)table;

    float2 res[NLVL];

    #pragma unroll
    for (int l = 0; l < NLVL; ++l) {
        const int   s  = 1 << l;          // compile-time per unrolled iter
        const float vs = (float)s;

        const float gx = nx * vs;
        const float gy = ny * vs;
        const float gz = nz * vs;

        const float bxf = floorf(gx);
        const float byf = floorf(gy);
        const float bzf = floorf(gz);

        const int ix = (int)bxf;
        const int iy = (int)byf;
        const int iz = (int)bzf;

        // (px - x1)/(x2 - x1) == frac(g) exactly (algebraic identity)
        const float tx = gx - bxf;
        const float ty = gy - byf;
        const float tz = gz - bzf;
        const float ux = 1.0f - tx;
        const float uy = 1.0f - ty;
        const float uz = 1.0f - tz;

        const int s2   = s * s;
        const int f000 = ix + iy * s + iz * s2;

        // 8 independent gathers -> deep MLP
        const float2 q0 = tb[f000];
        const float2 q1 = tb[f000 + 1];
        const float2 q2 = tb[f000 + s];
        const float2 q3 = tb[f000 + s + 1];
        const float2 q4 = tb[f000 + s2];
        const float2 q5 = tb[f000 + s2 + 1];
        const float2 q6 = tb[f000 + s2 + s];
        const float2 q7 = tb[f000 + s2 + s + 1];

        const float fx0a = ux * q0.x + tx * q1.x;
        const float fx0b = ux * q0.y + tx * q1.y;
        const float fx1a = ux * q2.x + tx * q3.x;
        const float fx1b = ux * q2.y + tx * q3.y;
        const float fx2a = ux * q4.x + tx * q5.x;
        const float fx2b = ux * q4.y + tx * q5.y;
        const float fx3a = ux * q6.x + tx * q7.x;
        const float fx3b = ux * q6.y + tx * q7.y;

        const float fy0a = uy * fx0a + ty * fx1a;
        const float fy0b = uy * fx0b + ty * fx1b;
        const float fy1a = uy * fx2a + ty * fx3a;
        const float fy1b = uy * fx2b + ty * fx3b;

        res[l].x = uz * fy0a + tz * fy1a;
        res[l].y = uz * fy0b + tz * fy1b;
    }

    // 72 B contiguous per thread; wave writes 4.6 KB contiguous span
    float2* o = (float2*)out + (size_t)p * NLVL;
    #pragma unroll
    for (int l = 0; l < NLVL; ++l) o[l] = res[l];
}

extern "C" void kernel_launch(void* const* d_in, const int* in_sizes, int n_in,
                              void* d_out, int out_size, void* d_ws, size_t ws_size,
                              hipStream_t stream) {
    const float* x     = (const float*)d_in[0];
    const float* table = (const float*)d_in[1];
    float* out = (float*)d_out;

    const int block = 256;
    const int grid  = (NPTS + block - 1) / block;
    enc_kernel<<<grid, block, 0, stream>>>(x, table, out);
}